// Round 6
// baseline (46.497 us; speedup 1.0000x reference)
//
#include <hip/hip_runtime.h>
#include <hip/hip_bf16.h>
#include <math.h>

#define RPB 26    // 64*520 rows = 1280 blocks * 26 -> 5 even rounds of 256 CUs
#define XSTR 24   // padded floats per token row in LDS (96 B, 16B-aligned)

typedef float f4 __attribute__((ext_vector_type(4)));
typedef float f2 __attribute__((ext_vector_type(2)));

// ---------------------------------------------------------------------------
// Setup: per-segment start/count tables from the sorted batch array.
// tables[0..63] = start of relabeled segment s; tables[64..127] = count.
// Handles int32/int64 device layouts (last word == 0 -> int64).
// ---------------------------------------------------------------------------
__global__ __launch_bounds__(1024) void setup_kernel(const int* __restrict__ batch,
                                                     int n, int* __restrict__ tables) {
  __shared__ int samp[256];
  __shared__ int csum[64];
  __shared__ int fine[64];
  __shared__ int sbase[64];
  __shared__ int lbs[65];
  __shared__ int stride_s;
  int t = threadIdx.x;
  if (t == 0) stride_s = (batch[n - 1] == 0) ? 2 : 1;
  if (t < 64) { csum[t] = 0; fine[t] = 0; }
  __syncthreads();
  int stride = stride_s;
  int window = (n + 255) >> 8;
  if (t < 256) {
    long long idx = (long long)t * window;
    if (idx > n - 1) idx = n - 1;
    samp[t] = batch[idx * stride];
  }
  __syncthreads();
  {
    int v = t >> 4, q = t & 15;
    int c = 0;
#pragma unroll
    for (int i = 0; i < 16; ++i) c += (samp[q * 16 + i] < v) ? 1 : 0;
    atomicAdd(&csum[v], c);
  }
  __syncthreads();
  if (t < 64) {
    int c = csum[t];
    sbase[t] = (c == 0) ? 0 : (c - 1) * window;
  }
  __syncthreads();
  {
    int v = t >> 4, q = t & 15;
    int wpt = (window + 15) >> 4;
    int S = sbase[v];
    int c = 0;
    for (int j = q * wpt; j < (q + 1) * wpt && j < window; ++j) {
      int idx = S + j;
      if (idx < n && batch[idx * stride] < v) c++;
    }
    atomicAdd(&fine[v], c);
  }
  __syncthreads();
  if (t < 64) {
    lbs[t] = sbase[t] + fine[t];
    if (t == 0) lbs[64] = n;
  }
  __syncthreads();
  if (t < 64) {
    int cnt = lbs[t + 1] - lbs[t];
    unsigned long long present = __ballot(cnt > 0);
    int seg = __popcll(present & ((1ull << t) - 1ull));
    int nseq = __popcll(present);
    if (cnt > 0) { tables[seg] = lbs[t]; tables[64 + seg] = cnt; }
    if (t >= nseq) { tables[t] = 0; tables[64 + t] = 0; }
  }
}

// ---------------------------------------------------------------------------
// Fused main. Block owns RPB consecutive padded rows; thread t owns dims
// [4t, 4t+4). Valid tokens of a block are globally consecutive, so x staging
// is one contiguous span -> padded LDS. Inner loop fully if-converted:
// unconditional 21x f2 packed FMAs (v_pk_fma_f32), LDS broadcast reads,
// rotation-recurrence PE, uniform cndmask select, one f4 store per row.
// h = (x.Wt + b)*32 + pe  computed as  x.(32*Wt) + (32*b) + pe.
// ---------------------------------------------------------------------------
__global__ __launch_bounds__(256) void embed_kernel(
    const float* __restrict__ x, const float* __restrict__ W,
    const float* __restrict__ b, const int* __restrict__ tables,
    float* __restrict__ out, float* __restrict__ mask,
    int L, int totalRows, int n_tokens) {
  int t = threadIdx.x;
  __shared__ __align__(16) float xs[RPB * XSTR];

  // ---- uniform block state
  int base = blockIdx.x * RPB;
  int s = base / L;
  int p0 = base - s * L;
  int st = tables[s];
  int cnt = tables[64 + s];
  int pc = p0 < cnt ? p0 : cnt;
  int t0 = st + pc;  // first candidate token; block's tokens are consecutive

  // ---- stage x[t0 .. t0+RPB) into padded LDS (RPB*21 dwords, linear source)
  {
    int gbase = t0 * 21;
    int glast = n_tokens * 21 - 1;
#pragma unroll
    for (int it = 0; it < 3; ++it) {
      int u = t + it * 256;
      if (u < RPB * 21) {
        int li = u / 21;
        int j = u - li * 21;
        int g = gbase + u;
        if (g > glast) g = glast;
        xs[li * XSTR + j] = x[g];
      }
    }
  }

  // ---- mask for this block's rows (threads 0..RPB-1), off the main loop
  if (t < RPB) {
    int row = base + t;
    if (row < totalRows) {
      int ss = row / L;
      int pp = row - ss * L;
      mask[row] = (pp < tables[64 + ss]) ? 1.0f : 0.0f;
    }
  }

  // ---- W rows 4t..4t+3, pre-scaled by 32, packed: w01[k]={W[4t][k],W[4t+1][k]}
  float arr[84];
  {
    const f4* wp = (const f4*)(W + 84 * t);
#pragma unroll
    for (int k = 0; k < 21; ++k) {
      f4 v = wp[k];
      arr[4 * k] = v[0] * 32.f; arr[4 * k + 1] = v[1] * 32.f;
      arr[4 * k + 2] = v[2] * 32.f; arr[4 * k + 3] = v[3] * 32.f;
    }
  }
  f2 w01[21], w23[21];
#pragma unroll
  for (int k = 0; k < 21; ++k) {
    f2 a; a[0] = arr[k];      a[1] = arr[21 + k]; w01[k] = a;
    f2 c; c[0] = arr[42 + k]; c[1] = arr[63 + k]; w23[k] = c;
  }
  f4 bb = *(const f4*)(b + 4 * t);
  f2 b01; b01[0] = bb[0] * 32.f; b01[1] = bb[1] * 32.f;
  f2 b23; b23[0] = bb[2] * 32.f; b23[1] = bb[3] * 32.f;

  // ---- PE rotation state: angles p*divA (dims 4t,4t+1), p*divB (4t+2,4t+3)
  const float KC = -0.01798894603901599f;  // -ln(10000)/512
  float divA = __expf(KC * (float)(2 * t));
  float divB = __expf(KC * (float)(2 * t + 1));
  float dsA, dcA, dsB, dcB, sA, cA, sB, cB;
  __sincosf(divA, &dsA, &dcA);
  __sincosf(divB, &dsB, &dcB);
  __sincosf((float)p0 * divA, &sA, &cA);
  __sincosf((float)p0 * divB, &sB, &cB);

  __syncthreads();

  int p = p0;
  int li = 0;
  float* po = out + (size_t)base * 1024 + 4 * t;

  // fast path: full block of RPB rows (all blocks when totalRows % RPB == 0)
  if (base + RPB <= totalRows) {
#pragma unroll 2
    for (int rr = 0; rr < RPB; ++rr) {
      bool valid = (p < cnt);
      const f4* xr = (const f4*)&xs[li * XSTR];
      f4 v0 = xr[0], v1 = xr[1], v2 = xr[2], v3 = xr[3], v4 = xr[4];
      float x20 = xs[li * XSTR + 20];
      f2 a01 = b01, a23 = b23;
#define STEP(K, XV) { f2 xv; xv[0] = (XV); xv[1] = (XV); \
      a01 = __builtin_elementwise_fma(xv, w01[K], a01); \
      a23 = __builtin_elementwise_fma(xv, w23[K], a23); }
#pragma unroll
      for (int q = 0; q < 4; ++q) STEP(q, v0[q]);
#pragma unroll
      for (int q = 0; q < 4; ++q) STEP(4 + q, v1[q]);
#pragma unroll
      for (int q = 0; q < 4; ++q) STEP(8 + q, v2[q]);
#pragma unroll
      for (int q = 0; q < 4; ++q) STEP(12 + q, v3[q]);
#pragma unroll
      for (int q = 0; q < 4; ++q) STEP(16 + q, v4[q]);
      STEP(20, x20);
#undef STEP
      f4 res;
      res[0] = valid ? (a01[0] + sA) : sA;
      res[1] = valid ? (a01[1] + cA) : cA;
      res[2] = valid ? (a23[0] + sB) : sB;
      res[3] = valid ? (a23[1] + cB) : cB;
      *(f4*)po = res;
      po += 1024;
      li += valid ? 1 : 0;

      if (rr + 1 < RPB) {
        ++p;
        if (p == L) {
          p = 0; ++s;
          st = tables[s]; cnt = tables[64 + s];
          sA = 0.f; cA = 1.f; sB = 0.f; cB = 1.f;
        } else {
          float nsA = fmaf(sA, dcA, cA * dsA);
          float ncA = fmaf(cA, dcA, -sA * dsA);
          float nsB = fmaf(sB, dcB, cB * dsB);
          float ncB = fmaf(cB, dcB, -sB * dsB);
          sA = nsA; cA = ncA; sB = nsB; cB = ncB;
        }
      }
    }
  } else {
    int nrows = totalRows - base;
    for (int rr = 0; rr < nrows; ++rr) {
      bool valid = (p < cnt);
      f4 res; res[0] = sA; res[1] = cA; res[2] = sB; res[3] = cB;
      if (valid) {
        const f4* xr = (const f4*)&xs[li * XSTR];
        f4 v0 = xr[0], v1 = xr[1], v2 = xr[2], v3 = xr[3], v4 = xr[4];
        float xk[21];
#pragma unroll
        for (int q = 0; q < 4; ++q) {
          xk[q] = v0[q]; xk[4 + q] = v1[q]; xk[8 + q] = v2[q]; xk[12 + q] = v3[q];
          xk[16 + q] = v4[q];
        }
        xk[20] = xs[li * XSTR + 20];
        float a0 = b01[0], a1 = b01[1], a2 = b23[0], a3 = b23[1];
#pragma unroll
        for (int k = 0; k < 21; ++k) {
          float xv = xk[k];
          a0 = fmaf(xv, w01[k][0], a0);
          a1 = fmaf(xv, w01[k][1], a1);
          a2 = fmaf(xv, w23[k][0], a2);
          a3 = fmaf(xv, w23[k][1], a3);
        }
        res[0] += a0; res[1] += a1; res[2] += a2; res[3] += a3;
        ++li;
      }
      *(f4*)po = res;
      po += 1024;
      if (rr + 1 < nrows) {
        ++p;
        if (p == L) {
          p = 0; ++s;
          st = tables[s]; cnt = tables[64 + s];
          sA = 0.f; cA = 1.f; sB = 0.f; cB = 1.f;
        } else {
          float nsA = fmaf(sA, dcA, cA * dsA);
          float ncA = fmaf(cA, dcA, -sA * dsA);
          float nsB = fmaf(sB, dcB, cB * dsB);
          float ncB = fmaf(cB, dcB, -sB * dsB);
          sA = nsA; cA = ncA; sB = nsB; cB = ncB;
        }
      }
    }
  }
}

extern "C" void kernel_launch(void* const* d_in, const int* in_sizes, int n_in,
                              void* d_out, int out_size, void* d_ws, size_t ws_size,
                              hipStream_t stream) {
  const float* x = (const float*)d_in[0];
  const float* W = (const float*)d_in[1];
  const float* b = (const float*)d_in[2];
  const int* batch = (const int*)d_in[3];
  int n_tokens = in_sizes[3];
  float* out = (float*)d_out;

  int L = out_size / (64 * 1025);
  int totalRows = 64 * L;

  int* tables = (int*)d_ws;

  setup_kernel<<<1, 1024, 0, stream>>>(batch, n_tokens, tables);
  int grid = (totalRows + RPB - 1) / RPB;
  embed_kernel<<<grid, 256, 0, stream>>>(x, W, b, tables, out,
                                         out + (size_t)totalRows * 1024,
                                         L, totalRows, n_tokens);
}